// Round 8
// baseline (239.515 us; speedup 1.0000x reference)
//
#include <hip/hip_runtime.h>
#include <hip/hip_bf16.h>

#define DMODEL 1024
#define NHEADS 16
#define HDIM 64

typedef __bf16 bf16_t;
typedef __bf16 bf16x8 __attribute__((ext_vector_type(8)));
typedef float  f32x4  __attribute__((ext_vector_type(4)));
typedef float  f32x16 __attribute__((ext_vector_type(16)));

__device__ __forceinline__ bf16_t f2bf(float f) {
    unsigned int u = __builtin_bit_cast(unsigned int, f);
    u += 0x7FFF + ((u >> 16) & 1);           // RNE
    unsigned short h = (unsigned short)(u >> 16);
    return __builtin_bit_cast(bf16_t, h);
}

__device__ __forceinline__ unsigned cvt_pk_bf16(float lo, float hi) {
    unsigned r;
    asm("v_cvt_pk_bf16_f32 %0, %1, %2" : "=v"(r) : "v"(lo), "v"(hi));
    return r;
}

__device__ __forceinline__ void gld_lds16(const bf16_t* g, bf16_t* l) {
    __builtin_amdgcn_global_load_lds(
        (const __attribute__((address_space(1))) unsigned int*)g,
        (__attribute__((address_space(3))) unsigned int*)l, 16, 0, 0);
}

// ---------------- fp32 -> bf16 cast: 4 weight matrices ----------------
__global__ __launch_bounds__(256) void cast4(const float* __restrict__ s0,
                                             const float* __restrict__ s1,
                                             const float* __restrict__ s2,
                                             const float* __restrict__ s3,
                                             bf16_t* __restrict__ d, int n) {
    int y = blockIdx.y;
    const float* s = (y == 0) ? s0 : (y == 1) ? s1 : (y == 2) ? s2 : s3;
    bf16_t* dst = d + (size_t)y * n;
    int i = blockIdx.x * blockDim.x + threadIdx.x;
    int stride = gridDim.x * blockDim.x;
    for (int idx = i * 4; idx < n; idx += stride * 4) {
        float4 v = *reinterpret_cast<const float4*>(s + idx);
        uint2 u;
        u.x = cvt_pk_bf16(v.x, v.y);
        u.y = cvt_pk_bf16(v.z, v.w);
        *reinterpret_cast<uint2*>(dst + idx) = u;
    }
}

// ---------------- fp32 -> bf16 cast: 3 activation inputs (q,k,v) ----------------
__global__ __launch_bounds__(256) void cast3(const float* __restrict__ q,
                                             const float* __restrict__ k,
                                             const float* __restrict__ v,
                                             bf16_t* __restrict__ qb,
                                             bf16_t* __restrict__ kb,
                                             bf16_t* __restrict__ vb, int n) {
    int z = blockIdx.y;
    const float* s = (z == 0) ? q : (z == 1) ? k : v;
    bf16_t* d = (z == 0) ? qb : (z == 1) ? kb : vb;
    int i = blockIdx.x * blockDim.x + threadIdx.x;
    int stride = gridDim.x * blockDim.x;
    for (int idx = i * 4; idx < n; idx += stride * 4) {
        float4 vv = *reinterpret_cast<const float4*>(s + idx);
        uint2 u;
        u.x = cvt_pk_bf16(vv.x, vv.y);
        u.y = cvt_pk_bf16(vv.z, vv.w);
        *reinterpret_cast<uint2*>(d + idx) = u;
    }
}

// ---------------- merged QKV projection GEMM (all-bf16 staging) ----------------
// grid = (M/128, 8, 3); z selects {A, W, bias, scale, output mode}.
// C[m,n] = (sum_k A[m,k]*W[n,k] + bias[n]) * scale ; z=0 -> Qp (scaled), z=1 -> Kp,
// z=2 -> VtG transposed [B,H,D,S].
__global__ __launch_bounds__(256) void gemm_qkv(const bf16_t* __restrict__ qb,
                                                const bf16_t* __restrict__ kb,
                                                const bf16_t* __restrict__ vb,
                                                const bf16_t* __restrict__ Wall,
                                                const float* __restrict__ bq,
                                                const float* __restrict__ bk,
                                                const float* __restrict__ bv,
                                                bf16_t* __restrict__ Qp,
                                                bf16_t* __restrict__ Kp,
                                                bf16_t* __restrict__ VtG,
                                                int M, float qscale, int S) {
    __shared__ bf16_t Asmem[2][128 * 32];
    __shared__ bf16_t Bsmem[2][128 * 32];
    const int K = DMODEL, N = DMODEL;
    const int z = blockIdx.z;
    const bf16_t* Ab = (z == 0) ? qb : (z == 1) ? kb : vb;
    const bf16_t* W = Wall + (size_t)z * DMODEL * DMODEL;
    const float* bias = (z == 0) ? bq : (z == 1) ? bk : bv;
    const float scale = (z == 0) ? qscale : 1.0f;

    const int m0 = blockIdx.x * 128;
    const int n0 = blockIdx.y * 128;
    const int tid = threadIdx.x;
    const int wave = tid >> 6, lane = tid & 63;
    const int wm = wave >> 1, wn = wave & 1;
    const int lr = lane & 15, lg = lane >> 4;
    const int srow = lane >> 2, scol = (lane & 3) * 8;

    f32x4 acc[4][4];
#pragma unroll
    for (int mi = 0; mi < 4; ++mi)
#pragma unroll
        for (int ni = 0; ni < 4; ++ni) acc[mi][ni] = (f32x4){0.f, 0.f, 0.f, 0.f};

#pragma unroll
    for (int i = 0; i < 2; ++i) {
        int c = wave * 2 + i;
        gld_lds16(Ab + (size_t)(m0 + c * 16 + srow) * K + scol, &Asmem[0][c * 512]);
        gld_lds16(W + (size_t)(n0 + c * 16 + srow) * K + scol, &Bsmem[0][c * 512]);
    }
    asm volatile("s_waitcnt vmcnt(0)" ::: "memory");
    __syncthreads();

    const int nk = K / 32;
    for (int t = 0; t < nk; ++t) {
        const int cur = t & 1, nxt = cur ^ 1;
        const int ktn = (t + 1) * 32;
        if (t + 1 < nk) {
#pragma unroll
            for (int i = 0; i < 2; ++i) {
                int c = wave * 2 + i;
                gld_lds16(Ab + (size_t)(m0 + c * 16 + srow) * K + ktn + scol, &Asmem[nxt][c * 512]);
                gld_lds16(W + (size_t)(n0 + c * 16 + srow) * K + ktn + scol, &Bsmem[nxt][c * 512]);
            }
        }
        bf16x8 af[4], bfr[4];
#pragma unroll
        for (int mi = 0; mi < 4; ++mi)
            af[mi] = *reinterpret_cast<const bf16x8*>(&Asmem[cur][(wm * 64 + mi * 16 + lr) * 32 + lg * 8]);
#pragma unroll
        for (int ni = 0; ni < 4; ++ni)
            bfr[ni] = *reinterpret_cast<const bf16x8*>(&Bsmem[cur][(wn * 64 + ni * 16 + lr) * 32 + lg * 8]);
#pragma unroll
        for (int mi = 0; mi < 4; ++mi)
#pragma unroll
            for (int ni = 0; ni < 4; ++ni)
                acc[mi][ni] = __builtin_amdgcn_mfma_f32_16x16x32_bf16(af[mi], bfr[ni], acc[mi][ni], 0, 0, 0);
        asm volatile("s_waitcnt vmcnt(0)" ::: "memory");
        __syncthreads();
    }

    // ---- epilogue ----
#pragma unroll
    for (int mi = 0; mi < 4; ++mi) {
        int row = m0 + wm * 64 + mi * 16 + lg * 4;
#pragma unroll
        for (int ni = 0; ni < 4; ++ni) {
            int col = n0 + wn * 64 + ni * 16 + lr;
            float bv_ = bias[col];
            if (z == 2) {   // transposed V output [B,H,D,S]
                union { bf16_t b[4]; uint2 u; } pq;
#pragma unroll
                for (int r = 0; r < 4; ++r) pq.b[r] = f2bf(acc[mi][ni][r] + bv_);
                int b_ = row / S, s_ = row % S;
                size_t addr = (((size_t)b_ * NHEADS + (col >> 6)) * HDIM + (col & 63)) * (size_t)S + s_;
                *reinterpret_cast<uint2*>(VtG + addr) = pq.u;
            } else {
                bf16_t* Cb = (z == 0) ? Qp : Kp;
#pragma unroll
                for (int r = 0; r < 4; ++r)
                    Cb[(size_t)(row + r) * N + col] = f2bf((acc[mi][ni][r] + bv_) * scale);
            }
        }
    }
}

// ---------------- output-projection GEMM (A bf16, out f32) ----------------
__global__ __launch_bounds__(256) void gemm_out(const bf16_t* __restrict__ Ab,
                                                const bf16_t* __restrict__ W,
                                                const float* __restrict__ bias,
                                                float* __restrict__ Cout,
                                                int M, int N, int K) {
    __shared__ bf16_t Asmem[2][128 * 32];
    __shared__ bf16_t Bsmem[2][128 * 32];
    const int m0 = blockIdx.x * 128;
    const int n0 = blockIdx.y * 128;
    const int tid = threadIdx.x;
    const int wave = tid >> 6, lane = tid & 63;
    const int wm = wave >> 1, wn = wave & 1;
    const int lr = lane & 15, lg = lane >> 4;
    const int srow = lane >> 2, scol = (lane & 3) * 8;

    f32x4 acc[4][4];
#pragma unroll
    for (int mi = 0; mi < 4; ++mi)
#pragma unroll
        for (int ni = 0; ni < 4; ++ni) acc[mi][ni] = (f32x4){0.f, 0.f, 0.f, 0.f};

#pragma unroll
    for (int i = 0; i < 2; ++i) {
        int c = wave * 2 + i;
        gld_lds16(Ab + (size_t)(m0 + c * 16 + srow) * K + scol, &Asmem[0][c * 512]);
        gld_lds16(W + (size_t)(n0 + c * 16 + srow) * K + scol, &Bsmem[0][c * 512]);
    }
    asm volatile("s_waitcnt vmcnt(0)" ::: "memory");
    __syncthreads();

    const int nk = K / 32;
    for (int t = 0; t < nk; ++t) {
        const int cur = t & 1, nxt = cur ^ 1;
        const int ktn = (t + 1) * 32;
        if (t + 1 < nk) {
#pragma unroll
            for (int i = 0; i < 2; ++i) {
                int c = wave * 2 + i;
                gld_lds16(Ab + (size_t)(m0 + c * 16 + srow) * K + ktn + scol, &Asmem[nxt][c * 512]);
                gld_lds16(W + (size_t)(n0 + c * 16 + srow) * K + ktn + scol, &Bsmem[nxt][c * 512]);
            }
        }
        bf16x8 af[4], bfr[4];
#pragma unroll
        for (int mi = 0; mi < 4; ++mi)
            af[mi] = *reinterpret_cast<const bf16x8*>(&Asmem[cur][(wm * 64 + mi * 16 + lr) * 32 + lg * 8]);
#pragma unroll
        for (int ni = 0; ni < 4; ++ni)
            bfr[ni] = *reinterpret_cast<const bf16x8*>(&Bsmem[cur][(wn * 64 + ni * 16 + lr) * 32 + lg * 8]);
#pragma unroll
        for (int mi = 0; mi < 4; ++mi)
#pragma unroll
            for (int ni = 0; ni < 4; ++ni)
                acc[mi][ni] = __builtin_amdgcn_mfma_f32_16x16x32_bf16(af[mi], bfr[ni], acc[mi][ni], 0, 0, 0);
        asm volatile("s_waitcnt vmcnt(0)" ::: "memory");
        __syncthreads();
    }

#pragma unroll
    for (int mi = 0; mi < 4; ++mi) {
        int row = m0 + wm * 64 + mi * 16 + lg * 4;
#pragma unroll
        for (int ni = 0; ni < 4; ++ni) {
            int col = n0 + wn * 64 + ni * 16 + lr;
            float bv = bias[col];
#pragma unroll
            for (int r = 0; r < 4; ++r)
                Cout[(size_t)(row + r) * N + col] = acc[mi][ni][r] + bv;
        }
    }
}

// ---------------- flash attention: 32x32 swapped-operand, lane-owns-q-row ----------------
// grid: x = S/128 (q tiles of 128), y = B*NHEADS. 256 threads = 4 waves, each 32 q rows.
// Qp/Kp: [B*S, DMODEL] bf16 (Q pre-scaled by 0.125*log2e). VtG: [B,H,D,S] bf16.
__global__ __launch_bounds__(256, 4) void attn_kernel(const bf16_t* __restrict__ Qp,
                                                      const bf16_t* __restrict__ Kp,
                                                      const bf16_t* __restrict__ VtG,
                                                      bf16_t* __restrict__ AO, int S) {
    __shared__ bf16_t KsA[64 * 64], KsB[64 * 64];   // [key][dim], 16B blocks XOR-swz (row&7)
    __shared__ bf16_t VtA[64 * 64], VtB[64 * 64];   // [dim][key], same swizzle
    const int tid = threadIdx.x;
    const int wave = tid >> 6, lane = tid & 63;
    const int ql = lane & 31;        // this lane's q (and D-col)
    const int hi = lane >> 5;
    const int bh = blockIdx.y;
    const int b = bh >> 4, h = bh & 15;
    const int qt = blockIdx.x;
    const size_t base = ((size_t)b * S) * DMODEL + (size_t)h * HDIM;
    const size_t vbase = (size_t)bh * HDIM * (size_t)S;

    const int qrow = qt * 128 + wave * 32 + ql;
    bf16x8 qf[4];
#pragma unroll
    for (int kc = 0; kc < 4; ++kc)
        qf[kc] = *reinterpret_cast<const bf16x8*>(Qp + base + (size_t)qrow * DMODEL + kc * 16 + hi * 8);

    f32x16 o0{}, o1{};               // O^T[d][q=ql]: o0 d=0..31, o1 d=32..63
    float m_r = -1e30f, l_r = 0.f;   // per-lane = per-q (log2 domain)

    const int r0 = tid >> 3;
    const int swz = ((tid & 7) ^ (r0 & 7)) * 8;
    const bf16_t* Kb = Kp + base;
    const bf16_t* Vb = VtG + vbase;

    auto stageK = [&](int kv, bf16_t* buf) {
        gld_lds16(Kb + (size_t)(kv + r0) * DMODEL + swz, buf + wave * 512);
        gld_lds16(Kb + (size_t)(kv + r0 + 32) * DMODEL + swz, buf + 2048 + wave * 512);
    };
    auto stageV = [&](int kv, bf16_t* buf) {
        gld_lds16(Vb + (size_t)r0 * S + kv + swz, buf + wave * 512);
        gld_lds16(Vb + (size_t)(r0 + 32) * S + kv + swz, buf + 2048 + wave * 512);
    };

    stageK(0, KsA);
    stageV(0, VtA);
    asm volatile("s_waitcnt vmcnt(0)" ::: "memory");
    __syncthreads();

    const int NT = S / 64;
    for (int t = 0; t < NT; ++t) {
        const bf16_t* Kc = (t & 1) ? KsB : KsA;
        const bf16_t* Vc = (t & 1) ? VtB : VtA;
        bf16_t* Kn = (t & 1) ? KsA : KsB;
        bf16_t* Vn = (t & 1) ? VtA : VtB;
        if (t + 1 < NT) {
            stageK((t + 1) * 64, Kn);
            stageV((t + 1) * 64, Vn);
        }

        // ---- QK^T: T[key][q] ; s0 = keys 0..31, s1 = keys 32..63 ----
        f32x16 s0{}, s1{};
        __builtin_amdgcn_s_setprio(1);
#pragma unroll
        for (int kc = 0; kc < 4; ++kc) {
            bf16x8 kf = *reinterpret_cast<const bf16x8*>(
                &Kc[ql * 64 + (((2 * kc + hi) ^ (ql & 7)) * 8)]);
            s0 = __builtin_amdgcn_mfma_f32_32x32x16_bf16(kf, qf[kc], s0, 0, 0, 0);
        }
#pragma unroll
        for (int kc = 0; kc < 4; ++kc) {
            bf16x8 kf = *reinterpret_cast<const bf16x8*>(
                &Kc[(32 + ql) * 64 + (((2 * kc + hi) ^ (ql & 7)) * 8)]);
            s1 = __builtin_amdgcn_mfma_f32_32x32x16_bf16(kf, qf[kc], s1, 0, 0, 0);
        }
        __builtin_amdgcn_s_setprio(0);

        // ---- in-lane softmax ----
        float mx = s0[0];
#pragma unroll
        for (int r = 1; r < 16; ++r) mx = fmaxf(mx, s0[r]);
#pragma unroll
        for (int r = 0; r < 16; ++r) mx = fmaxf(mx, s1[r]);
        mx = fmaxf(mx, __shfl_xor(mx, 32, 64));

        if (!__all(mx <= m_r + 8.f)) {   // T13 defer-max
            float mnew = fmaxf(m_r, mx);
            float fsc = __builtin_amdgcn_exp2f(m_r - mnew);
            l_r *= fsc;
            m_r = mnew;
#pragma unroll
            for (int r = 0; r < 16; ++r) { o0[r] *= fsc; o1[r] *= fsc; }
        }

        float p0[16], p1[16];
        float ssum = 0.f;
#pragma unroll
        for (int r = 0; r < 16; ++r) {
            p0[r] = __builtin_amdgcn_exp2f(s0[r] - m_r);
            p1[r] = __builtin_amdgcn_exp2f(s1[r] - m_r);
            ssum += p0[r] + p1[r];
        }
        ssum += __shfl_xor(ssum, 32, 64);
        l_r += ssum;

        // ---- pack P: w[j][i] = keys {8j+4hi+2i, +1} of q=ql ----
        unsigned w[8][2];
#pragma unroll
        for (int j = 0; j < 4; ++j) {
            w[j][0] = cvt_pk_bf16(p0[4 * j], p0[4 * j + 1]);
            w[j][1] = cvt_pk_bf16(p0[4 * j + 2], p0[4 * j + 3]);
            w[4 + j][0] = cvt_pk_bf16(p1[4 * j], p1[4 * j + 1]);
            w[4 + j][1] = cvt_pk_bf16(p1[4 * j + 2], p1[4 * j + 3]);
        }

        // ---- PV: per K-chunk kq, B-frag P^T[key=16kq+8hi+e][q=ql] ----
#pragma unroll
        for (int kq = 0; kq < 4; ++kq) {
            unsigned own0 = hi ? w[2 * kq + 1][0] : w[2 * kq][0];
            unsigned own1 = hi ? w[2 * kq + 1][1] : w[2 * kq][1];
            unsigned y0 = hi ? w[2 * kq][0] : w[2 * kq + 1][0];
            unsigned y1 = hi ? w[2 * kq][1] : w[2 * kq + 1][1];
            y0 = (unsigned)__shfl_xor((int)y0, 32, 64);
            y1 = (unsigned)__shfl_xor((int)y1, 32, 64);
            union { unsigned u[4]; bf16x8 v; } pb;
            pb.u[0] = hi ? y0 : own0;
            pb.u[1] = hi ? y1 : own1;
            pb.u[2] = hi ? own0 : y0;
            pb.u[3] = hi ? own1 : y1;
            bf16x8 vf0 = *reinterpret_cast<const bf16x8*>(
                &Vc[ql * 64 + (((2 * kq + hi) ^ (ql & 7)) * 8)]);
            bf16x8 vf1 = *reinterpret_cast<const bf16x8*>(
                &Vc[(32 + ql) * 64 + (((2 * kq + hi) ^ (ql & 7)) * 8)]);
            __builtin_amdgcn_s_setprio(1);
            o0 = __builtin_amdgcn_mfma_f32_32x32x16_bf16(vf0, pb.v, o0, 0, 0, 0);
            o1 = __builtin_amdgcn_mfma_f32_32x32x16_bf16(vf1, pb.v, o1, 0, 0, 0);
            __builtin_amdgcn_s_setprio(0);
        }

        asm volatile("s_waitcnt vmcnt(0)" ::: "memory");
        __syncthreads();
    }

    // ---- epilogue: reg r -> d=(r&3)+8*(r>>2)+4*hi (+32 for o1) ----
    float inv = 1.f / l_r;
    bf16_t* Ao = AO + base + (size_t)qrow * DMODEL;
#pragma unroll
    for (int j = 0; j < 4; ++j) {
        uint2 u0, u1;
        u0.x = cvt_pk_bf16(o0[4 * j] * inv, o0[4 * j + 1] * inv);
        u0.y = cvt_pk_bf16(o0[4 * j + 2] * inv, o0[4 * j + 3] * inv);
        *reinterpret_cast<uint2*>(Ao + 8 * j + 4 * hi) = u0;
        u1.x = cvt_pk_bf16(o1[4 * j] * inv, o1[4 * j + 1] * inv);
        u1.y = cvt_pk_bf16(o1[4 * j + 2] * inv, o1[4 * j + 3] * inv);
        *reinterpret_cast<uint2*>(Ao + 32 + 8 * j + 4 * hi) = u1;
    }
}

extern "C" void kernel_launch(void* const* d_in, const int* in_sizes, int n_in,
                              void* d_out, int out_size, void* d_ws, size_t ws_size,
                              hipStream_t stream) {
    const float* q  = (const float*)d_in[0];
    const float* k  = (const float*)d_in[1];
    const float* v  = (const float*)d_in[2];
    const float* Wq = (const float*)d_in[3];
    const float* bq = (const float*)d_in[4];
    const float* Wk = (const float*)d_in[5];
    const float* bk = (const float*)d_in[6];
    const float* Wv = (const float*)d_in[7];
    const float* bv = (const float*)d_in[8];
    const float* Wo = (const float*)d_in[9];
    const float* bo = (const float*)d_in[10];

    const int M = in_sizes[0] / DMODEL;   // B*S
    const int S = 2048;
    const int B = M / S;

    // Workspace layout (lifetime-aliased to stay within ~76 MB):
    //   ws:    Wall(4*WSZ bf16) | Qp | Kp | VtG | sharedX (vb then AO)
    //   d_out: qb | kb  (bf16; dead before gemm_out writes fp32 output)
    bf16_t* ws  = (bf16_t*)d_ws;
    const size_t WSZ = (size_t)DMODEL * DMODEL;
    const size_t MSZ = (size_t)M * DMODEL;
    bf16_t* Wqb = ws;                      // Wall = [Wq|Wk|Wv|Wo] bf16
    bf16_t* Wob = Wqb + 3 * WSZ;
    bf16_t* Qp  = Wob + WSZ;
    bf16_t* Kp  = Qp + MSZ;
    bf16_t* VtG = Kp + MSZ;
    bf16_t* shX = VtG + MSZ;               // vb (cast->gemm_qkv), then AO (attn->gemm_out)
    bf16_t* qb  = (bf16_t*)d_out;          // M*DMODEL bf16 = out bytes / 2
    bf16_t* kb  = qb + MSZ;                // fills d_out exactly (M*DMODEL*4 bytes)
    bf16_t* vb  = shX;
    bf16_t* AO  = shX;

    cast4<<<dim3(1024, 4), 256, 0, stream>>>(Wq, Wk, Wv, Wo, ws, DMODEL * DMODEL);
    cast3<<<dim3(2048, 3), 256, 0, stream>>>(q, k, v, qb, kb, vb, M * DMODEL);

    const float qscale = 0.125f * 1.44269504088896f;   // 1/sqrt(64) * log2(e)
    gemm_qkv<<<dim3(M / 128, DMODEL / 128, 3), 256, 0, stream>>>(
        qb, kb, vb, Wqb, bq, bk, bv, Qp, Kp, VtG, M, qscale, S);

    attn_kernel<<<dim3(S / 128, B * NHEADS), 256, 0, stream>>>(Qp, Kp, VtG, AO, S);

    gemm_out<<<dim3(M / 128, DMODEL / 128), 256, 0, stream>>>(
        AO, Wob, bo, (float*)d_out, M, DMODEL, DMODEL);
}

// Round 9
// 230.830 us; speedup vs baseline: 1.0376x; 1.0376x over previous
//
#include <hip/hip_runtime.h>
#include <hip/hip_bf16.h>

#define DMODEL 1024
#define NHEADS 16
#define HDIM 64

typedef __bf16 bf16_t;
typedef __bf16 bf16x8 __attribute__((ext_vector_type(8)));
typedef float  f32x4  __attribute__((ext_vector_type(4)));
typedef float  f32x16 __attribute__((ext_vector_type(16)));

__device__ __forceinline__ bf16_t f2bf(float f) {
    unsigned int u = __builtin_bit_cast(unsigned int, f);
    u += 0x7FFF + ((u >> 16) & 1);           // RNE
    unsigned short h = (unsigned short)(u >> 16);
    return __builtin_bit_cast(bf16_t, h);
}

__device__ __forceinline__ unsigned cvt_pk_bf16(float lo, float hi) {
    unsigned r;
    asm("v_cvt_pk_bf16_f32 %0, %1, %2" : "=v"(r) : "v"(lo), "v"(hi));
    return r;
}

__device__ __forceinline__ void gld_lds16(const bf16_t* g, bf16_t* l) {
    __builtin_amdgcn_global_load_lds(
        (const __attribute__((address_space(1))) unsigned int*)g,
        (__attribute__((address_space(3))) unsigned int*)l, 16, 0, 0);
}

// ---------------- fp32 -> bf16 cast: 4 weights + 3 activations, one launch ----------------
__global__ __launch_bounds__(256) void cast_all(const float* __restrict__ Wq,
                                                const float* __restrict__ Wk,
                                                const float* __restrict__ Wv,
                                                const float* __restrict__ Wo,
                                                const float* __restrict__ q,
                                                const float* __restrict__ k,
                                                const float* __restrict__ v,
                                                bf16_t* __restrict__ Wall,
                                                bf16_t* __restrict__ qb,
                                                bf16_t* __restrict__ kb,
                                                bf16_t* __restrict__ vb,
                                                int nw, int na) {
    const int y = blockIdx.y;
    const float* s;
    bf16_t* d;
    int n;
    if (y == 0)      { s = Wq; d = Wall;               n = nw; }
    else if (y == 1) { s = Wk; d = Wall + (size_t)nw;  n = nw; }
    else if (y == 2) { s = Wv; d = Wall + 2 * (size_t)nw; n = nw; }
    else if (y == 3) { s = Wo; d = Wall + 3 * (size_t)nw; n = nw; }
    else if (y == 4) { s = q;  d = qb; n = na; }
    else if (y == 5) { s = k;  d = kb; n = na; }
    else             { s = v;  d = vb; n = na; }
    int i = blockIdx.x * blockDim.x + threadIdx.x;
    int stride = gridDim.x * blockDim.x;
    for (int idx = i * 4; idx < n; idx += stride * 4) {
        float4 vv = *reinterpret_cast<const float4*>(s + idx);
        uint2 u;
        u.x = cvt_pk_bf16(vv.x, vv.y);
        u.y = cvt_pk_bf16(vv.z, vv.w);
        *reinterpret_cast<uint2*>(d + idx) = u;
    }
}

// ---------------- merged QKV projection GEMM (all-bf16 staging) ----------------
// grid = (M/128, 8, 3); z selects {A, W, bias, scale, output mode}.
__global__ __launch_bounds__(256) void gemm_qkv(const bf16_t* __restrict__ qb,
                                                const bf16_t* __restrict__ kb,
                                                const bf16_t* __restrict__ vb,
                                                const bf16_t* __restrict__ Wall,
                                                const float* __restrict__ bq,
                                                const float* __restrict__ bk,
                                                const float* __restrict__ bv,
                                                bf16_t* __restrict__ Qp,
                                                bf16_t* __restrict__ Kp,
                                                bf16_t* __restrict__ VtG,
                                                int M, float qscale, int S) {
    __shared__ bf16_t Asmem[2][128 * 32];
    __shared__ bf16_t Bsmem[2][128 * 32];
    const int K = DMODEL, N = DMODEL;
    const int z = blockIdx.z;
    const bf16_t* Ab = (z == 0) ? qb : (z == 1) ? kb : vb;
    const bf16_t* W = Wall + (size_t)z * DMODEL * DMODEL;
    const float* bias = (z == 0) ? bq : (z == 1) ? bk : bv;
    const float scale = (z == 0) ? qscale : 1.0f;

    const int m0 = blockIdx.x * 128;
    const int n0 = blockIdx.y * 128;
    const int tid = threadIdx.x;
    const int wave = tid >> 6, lane = tid & 63;
    const int wm = wave >> 1, wn = wave & 1;
    const int lr = lane & 15, lg = lane >> 4;
    const int srow = lane >> 2, scol = (lane & 3) * 8;

    f32x4 acc[4][4];
#pragma unroll
    for (int mi = 0; mi < 4; ++mi)
#pragma unroll
        for (int ni = 0; ni < 4; ++ni) acc[mi][ni] = (f32x4){0.f, 0.f, 0.f, 0.f};

#pragma unroll
    for (int i = 0; i < 2; ++i) {
        int c = wave * 2 + i;
        gld_lds16(Ab + (size_t)(m0 + c * 16 + srow) * K + scol, &Asmem[0][c * 512]);
        gld_lds16(W + (size_t)(n0 + c * 16 + srow) * K + scol, &Bsmem[0][c * 512]);
    }
    asm volatile("s_waitcnt vmcnt(0)" ::: "memory");
    __syncthreads();

    const int nk = K / 32;
    for (int t = 0; t < nk; ++t) {
        const int cur = t & 1, nxt = cur ^ 1;
        const int ktn = (t + 1) * 32;
        if (t + 1 < nk) {
#pragma unroll
            for (int i = 0; i < 2; ++i) {
                int c = wave * 2 + i;
                gld_lds16(Ab + (size_t)(m0 + c * 16 + srow) * K + ktn + scol, &Asmem[nxt][c * 512]);
                gld_lds16(W + (size_t)(n0 + c * 16 + srow) * K + ktn + scol, &Bsmem[nxt][c * 512]);
            }
        }
        bf16x8 af[4], bfr[4];
#pragma unroll
        for (int mi = 0; mi < 4; ++mi)
            af[mi] = *reinterpret_cast<const bf16x8*>(&Asmem[cur][(wm * 64 + mi * 16 + lr) * 32 + lg * 8]);
#pragma unroll
        for (int ni = 0; ni < 4; ++ni)
            bfr[ni] = *reinterpret_cast<const bf16x8*>(&Bsmem[cur][(wn * 64 + ni * 16 + lr) * 32 + lg * 8]);
#pragma unroll
        for (int mi = 0; mi < 4; ++mi)
#pragma unroll
            for (int ni = 0; ni < 4; ++ni)
                acc[mi][ni] = __builtin_amdgcn_mfma_f32_16x16x32_bf16(af[mi], bfr[ni], acc[mi][ni], 0, 0, 0);
        asm volatile("s_waitcnt vmcnt(0)" ::: "memory");
        __syncthreads();
    }

#pragma unroll
    for (int mi = 0; mi < 4; ++mi) {
        int row = m0 + wm * 64 + mi * 16 + lg * 4;
#pragma unroll
        for (int ni = 0; ni < 4; ++ni) {
            int col = n0 + wn * 64 + ni * 16 + lr;
            float bv_ = bias[col];
            if (z == 2) {   // transposed V output [B,H,D,S]
                union { bf16_t b[4]; uint2 u; } pq;
#pragma unroll
                for (int r = 0; r < 4; ++r) pq.b[r] = f2bf(acc[mi][ni][r] + bv_);
                int b_ = row / S, s_ = row % S;
                size_t addr = (((size_t)b_ * NHEADS + (col >> 6)) * HDIM + (col & 63)) * (size_t)S + s_;
                *reinterpret_cast<uint2*>(VtG + addr) = pq.u;
            } else {
                bf16_t* Cb = (z == 0) ? Qp : Kp;
#pragma unroll
                for (int r = 0; r < 4; ++r)
                    Cb[(size_t)(row + r) * N + col] = f2bf((acc[mi][ni][r] + bv_) * scale);
            }
        }
    }
}

// ---------------- output-projection GEMM (A bf16, out f32) ----------------
__global__ __launch_bounds__(256) void gemm_out(const bf16_t* __restrict__ Ab,
                                                const bf16_t* __restrict__ W,
                                                const float* __restrict__ bias,
                                                float* __restrict__ Cout,
                                                int M, int N, int K) {
    __shared__ bf16_t Asmem[2][128 * 32];
    __shared__ bf16_t Bsmem[2][128 * 32];
    const int m0 = blockIdx.x * 128;
    const int n0 = blockIdx.y * 128;
    const int tid = threadIdx.x;
    const int wave = tid >> 6, lane = tid & 63;
    const int wm = wave >> 1, wn = wave & 1;
    const int lr = lane & 15, lg = lane >> 4;
    const int srow = lane >> 2, scol = (lane & 3) * 8;

    f32x4 acc[4][4];
#pragma unroll
    for (int mi = 0; mi < 4; ++mi)
#pragma unroll
        for (int ni = 0; ni < 4; ++ni) acc[mi][ni] = (f32x4){0.f, 0.f, 0.f, 0.f};

#pragma unroll
    for (int i = 0; i < 2; ++i) {
        int c = wave * 2 + i;
        gld_lds16(Ab + (size_t)(m0 + c * 16 + srow) * K + scol, &Asmem[0][c * 512]);
        gld_lds16(W + (size_t)(n0 + c * 16 + srow) * K + scol, &Bsmem[0][c * 512]);
    }
    asm volatile("s_waitcnt vmcnt(0)" ::: "memory");
    __syncthreads();

    const int nk = K / 32;
    for (int t = 0; t < nk; ++t) {
        const int cur = t & 1, nxt = cur ^ 1;
        const int ktn = (t + 1) * 32;
        if (t + 1 < nk) {
#pragma unroll
            for (int i = 0; i < 2; ++i) {
                int c = wave * 2 + i;
                gld_lds16(Ab + (size_t)(m0 + c * 16 + srow) * K + ktn + scol, &Asmem[nxt][c * 512]);
                gld_lds16(W + (size_t)(n0 + c * 16 + srow) * K + ktn + scol, &Bsmem[nxt][c * 512]);
            }
        }
        bf16x8 af[4], bfr[4];
#pragma unroll
        for (int mi = 0; mi < 4; ++mi)
            af[mi] = *reinterpret_cast<const bf16x8*>(&Asmem[cur][(wm * 64 + mi * 16 + lr) * 32 + lg * 8]);
#pragma unroll
        for (int ni = 0; ni < 4; ++ni)
            bfr[ni] = *reinterpret_cast<const bf16x8*>(&Bsmem[cur][(wn * 64 + ni * 16 + lr) * 32 + lg * 8]);
#pragma unroll
        for (int mi = 0; mi < 4; ++mi)
#pragma unroll
            for (int ni = 0; ni < 4; ++ni)
                acc[mi][ni] = __builtin_amdgcn_mfma_f32_16x16x32_bf16(af[mi], bfr[ni], acc[mi][ni], 0, 0, 0);
        asm volatile("s_waitcnt vmcnt(0)" ::: "memory");
        __syncthreads();
    }

#pragma unroll
    for (int mi = 0; mi < 4; ++mi) {
        int row = m0 + wm * 64 + mi * 16 + lg * 4;
#pragma unroll
        for (int ni = 0; ni < 4; ++ni) {
            int col = n0 + wn * 64 + ni * 16 + lr;
            float bv = bias[col];
#pragma unroll
            for (int r = 0; r < 4; ++r)
                Cout[(size_t)(row + r) * N + col] = acc[mi][ni][r] + bv;
        }
    }
}

// ---------------- flash attention: 32x32 swapped-operand, 2 q-sets per wave (ILP) ----------------
// grid: x = S/256 (q tiles of 256), y = B*NHEADS. 256 threads = 4 waves.
// Wave w owns q-rows {qt*256 + w*32 + ql} (set A) and {+128} (set B): two independent
// softmax/O chains sharing the SAME K/V LDS reads, staging, and barriers.
__global__ __launch_bounds__(256, 2) void attn_kernel(const bf16_t* __restrict__ Qp,
                                                      const bf16_t* __restrict__ Kp,
                                                      const bf16_t* __restrict__ VtG,
                                                      bf16_t* __restrict__ AO, int S) {
    __shared__ bf16_t KsA[64 * 64], KsB[64 * 64];   // [key][dim], 16B blocks XOR-swz (row&7)
    __shared__ bf16_t VtA[64 * 64], VtB[64 * 64];   // [dim][key], same swizzle
    const int tid = threadIdx.x;
    const int wave = tid >> 6, lane = tid & 63;
    const int ql = lane & 31;        // this lane's q (and D-col)
    const int hi = lane >> 5;
    const int bh = blockIdx.y;
    const int b = bh >> 4, h = bh & 15;
    const int qt = blockIdx.x;
    const size_t base = ((size_t)b * S) * DMODEL + (size_t)h * HDIM;
    const size_t vbase = (size_t)bh * HDIM * (size_t)S;

    const int qrowA = qt * 256 + wave * 32 + ql;
    const int qrowB = qrowA + 128;
    bf16x8 qfA[4], qfB[4];
#pragma unroll
    for (int kc = 0; kc < 4; ++kc) {
        qfA[kc] = *reinterpret_cast<const bf16x8*>(Qp + base + (size_t)qrowA * DMODEL + kc * 16 + hi * 8);
        qfB[kc] = *reinterpret_cast<const bf16x8*>(Qp + base + (size_t)qrowB * DMODEL + kc * 16 + hi * 8);
    }

    f32x16 oA0{}, oA1{}, oB0{}, oB1{};   // O^T[d][q=ql] per set: *0 d=0..31, *1 d=32..63
    float mA = -1e30f, lA = 0.f;
    float mB = -1e30f, lB = 0.f;

    const int r0 = tid >> 3;
    const int swz = ((tid & 7) ^ (r0 & 7)) * 8;
    const bf16_t* Kb = Kp + base;
    const bf16_t* Vb = VtG + vbase;

    auto stageK = [&](int kv, bf16_t* buf) {
        gld_lds16(Kb + (size_t)(kv + r0) * DMODEL + swz, buf + wave * 512);
        gld_lds16(Kb + (size_t)(kv + r0 + 32) * DMODEL + swz, buf + 2048 + wave * 512);
    };
    auto stageV = [&](int kv, bf16_t* buf) {
        gld_lds16(Vb + (size_t)r0 * S + kv + swz, buf + wave * 512);
        gld_lds16(Vb + (size_t)(r0 + 32) * S + kv + swz, buf + 2048 + wave * 512);
    };

    // in-lane online softmax for one set; emits packed P words w[j][i]
    auto softmax_pack = [&](f32x16& s0, f32x16& s1, f32x16& o0, f32x16& o1,
                            float& m_r, float& l_r, unsigned (&w)[8][2]) {
        float mx = s0[0];
#pragma unroll
        for (int r = 1; r < 16; ++r) mx = fmaxf(mx, s0[r]);
#pragma unroll
        for (int r = 0; r < 16; ++r) mx = fmaxf(mx, s1[r]);
        mx = fmaxf(mx, __shfl_xor(mx, 32, 64));
        if (!__all(mx <= m_r + 8.f)) {   // T13 defer-max
            float mnew = fmaxf(m_r, mx);
            float fsc = __builtin_amdgcn_exp2f(m_r - mnew);
            l_r *= fsc;
            m_r = mnew;
#pragma unroll
            for (int r = 0; r < 16; ++r) { o0[r] *= fsc; o1[r] *= fsc; }
        }
        float p0[16], p1[16];
        float ssum = 0.f;
#pragma unroll
        for (int r = 0; r < 16; ++r) {
            p0[r] = __builtin_amdgcn_exp2f(s0[r] - m_r);
            p1[r] = __builtin_amdgcn_exp2f(s1[r] - m_r);
            ssum += p0[r] + p1[r];
        }
        ssum += __shfl_xor(ssum, 32, 64);
        l_r += ssum;
#pragma unroll
        for (int j = 0; j < 4; ++j) {
            w[j][0] = cvt_pk_bf16(p0[4 * j], p0[4 * j + 1]);
            w[j][1] = cvt_pk_bf16(p0[4 * j + 2], p0[4 * j + 3]);
            w[4 + j][0] = cvt_pk_bf16(p1[4 * j], p1[4 * j + 1]);
            w[4 + j][1] = cvt_pk_bf16(p1[4 * j + 2], p1[4 * j + 3]);
        }
    };

    // build PV B-fragment for chunk kq from packed words (verified r6 mapping)
    auto build_pb = [&](unsigned (&w)[8][2], int kq) {
        unsigned own0 = hi ? w[2 * kq + 1][0] : w[2 * kq][0];
        unsigned own1 = hi ? w[2 * kq + 1][1] : w[2 * kq][1];
        unsigned y0 = hi ? w[2 * kq][0] : w[2 * kq + 1][0];
        unsigned y1 = hi ? w[2 * kq][1] : w[2 * kq + 1][1];
        y0 = (unsigned)__shfl_xor((int)y0, 32, 64);
        y1 = (unsigned)__shfl_xor((int)y1, 32, 64);
        union { unsigned u[4]; bf16x8 v; } pb;
        pb.u[0] = hi ? y0 : own0;
        pb.u[1] = hi ? y1 : own1;
        pb.u[2] = hi ? own0 : y0;
        pb.u[3] = hi ? own1 : y1;
        return pb.v;
    };

    const int NT = S / 64;
    // one KV tile: process from (Kc,Vc), prefetch t+1 into (Kn,Vn)
    auto tile = [&](const bf16_t* Kc, const bf16_t* Vc, bf16_t* Kn, bf16_t* Vn, int t) {
        if (t + 1 < NT) {
            stageK((t + 1) * 64, Kn);
            stageV((t + 1) * 64, Vn);
        }
        // QK^T both sets, shared kf reads
        f32x16 sA0{}, sA1{}, sB0{}, sB1{};
        __builtin_amdgcn_s_setprio(1);
#pragma unroll
        for (int kc = 0; kc < 4; ++kc) {
            bf16x8 kf0 = *reinterpret_cast<const bf16x8*>(
                &Kc[ql * 64 + (((2 * kc + hi) ^ (ql & 7)) * 8)]);
            sA0 = __builtin_amdgcn_mfma_f32_32x32x16_bf16(kf0, qfA[kc], sA0, 0, 0, 0);
            sB0 = __builtin_amdgcn_mfma_f32_32x32x16_bf16(kf0, qfB[kc], sB0, 0, 0, 0);
            bf16x8 kf1 = *reinterpret_cast<const bf16x8*>(
                &Kc[(32 + ql) * 64 + (((2 * kc + hi) ^ (ql & 7)) * 8)]);
            sA1 = __builtin_amdgcn_mfma_f32_32x32x16_bf16(kf1, qfA[kc], sA1, 0, 0, 0);
            sB1 = __builtin_amdgcn_mfma_f32_32x32x16_bf16(kf1, qfB[kc], sB1, 0, 0, 0);
        }
        __builtin_amdgcn_s_setprio(0);

        unsigned wA[8][2], wB[8][2];
        softmax_pack(sA0, sA1, oA0, oA1, mA, lA, wA);
        softmax_pack(sB0, sB1, oB0, oB1, mB, lB, wB);

        // PV both sets, shared vf reads
#pragma unroll
        for (int kq = 0; kq < 4; ++kq) {
            bf16x8 pbA = build_pb(wA, kq);
            bf16x8 pbB = build_pb(wB, kq);
            bf16x8 vf0 = *reinterpret_cast<const bf16x8*>(
                &Vc[ql * 64 + (((2 * kq + hi) ^ (ql & 7)) * 8)]);
            bf16x8 vf1 = *reinterpret_cast<const bf16x8*>(
                &Vc[(32 + ql) * 64 + (((2 * kq + hi) ^ (ql & 7)) * 8)]);
            __builtin_amdgcn_s_setprio(1);
            oA0 = __builtin_amdgcn_mfma_f32_32x32x16_bf16(vf0, pbA, oA0, 0, 0, 0);
            oA1 = __builtin_amdgcn_mfma_f32_32x32x16_bf16(vf1, pbA, oA1, 0, 0, 0);
            oB0 = __builtin_amdgcn_mfma_f32_32x32x16_bf16(vf0, pbB, oB0, 0, 0, 0);
            oB1 = __builtin_amdgcn_mfma_f32_32x32x16_bf16(vf1, pbB, oB1, 0, 0, 0);
            __builtin_amdgcn_s_setprio(0);
        }
        asm volatile("s_waitcnt vmcnt(0)" ::: "memory");
        __syncthreads();
    };

    // prologue: stage tile 0
    stageK(0, KsA);
    stageV(0, VtA);
    asm volatile("s_waitcnt vmcnt(0)" ::: "memory");
    __syncthreads();

    for (int t = 0; t < NT; t += 2) {
        tile(KsA, VtA, KsB, VtB, t);
        tile(KsB, VtB, KsA, VtA, t + 1);
    }

    // ---- epilogue: reg r -> d=(r&3)+8*(r>>2)+4*hi (+32 for *1) ----
    {
        float inv = 1.f / lA;
        bf16_t* Ao = AO + base + (size_t)qrowA * DMODEL;
#pragma unroll
        for (int j = 0; j < 4; ++j) {
            uint2 u0, u1;
            u0.x = cvt_pk_bf16(oA0[4 * j] * inv, oA0[4 * j + 1] * inv);
            u0.y = cvt_pk_bf16(oA0[4 * j + 2] * inv, oA0[4 * j + 3] * inv);
            *reinterpret_cast<uint2*>(Ao + 8 * j + 4 * hi) = u0;
            u1.x = cvt_pk_bf16(oA1[4 * j] * inv, oA1[4 * j + 1] * inv);
            u1.y = cvt_pk_bf16(oA1[4 * j + 2] * inv, oA1[4 * j + 3] * inv);
            *reinterpret_cast<uint2*>(Ao + 32 + 8 * j + 4 * hi) = u1;
        }
    }
    {
        float inv = 1.f / lB;
        bf16_t* Ao = AO + base + (size_t)qrowB * DMODEL;
#pragma unroll
        for (int j = 0; j < 4; ++j) {
            uint2 u0, u1;
            u0.x = cvt_pk_bf16(oB0[4 * j] * inv, oB0[4 * j + 1] * inv);
            u0.y = cvt_pk_bf16(oB0[4 * j + 2] * inv, oB0[4 * j + 3] * inv);
            *reinterpret_cast<uint2*>(Ao + 8 * j + 4 * hi) = u0;
            u1.x = cvt_pk_bf16(oB1[4 * j] * inv, oB1[4 * j + 1] * inv);
            u1.y = cvt_pk_bf16(oB1[4 * j + 2] * inv, oB1[4 * j + 3] * inv);
            *reinterpret_cast<uint2*>(Ao + 32 + 8 * j + 4 * hi) = u1;
        }
    }
}

extern "C" void kernel_launch(void* const* d_in, const int* in_sizes, int n_in,
                              void* d_out, int out_size, void* d_ws, size_t ws_size,
                              hipStream_t stream) {
    const float* q  = (const float*)d_in[0];
    const float* k  = (const float*)d_in[1];
    const float* v  = (const float*)d_in[2];
    const float* Wq = (const float*)d_in[3];
    const float* bq = (const float*)d_in[4];
    const float* Wk = (const float*)d_in[5];
    const float* bk = (const float*)d_in[6];
    const float* Wv = (const float*)d_in[7];
    const float* bv = (const float*)d_in[8];
    const float* Wo = (const float*)d_in[9];
    const float* bo = (const float*)d_in[10];

    const int M = in_sizes[0] / DMODEL;   // B*S
    const int S = 2048;
    const int B = M / S;

    // Workspace layout (lifetime-aliased):
    //   ws:    Wall(4*WSZ bf16) | Qp | Kp | VtG | sharedX (vb then AO)
    //   d_out: qb | kb  (bf16; dead before gemm_out writes fp32 output)
    bf16_t* ws  = (bf16_t*)d_ws;
    const size_t WSZ = (size_t)DMODEL * DMODEL;
    const size_t MSZ = (size_t)M * DMODEL;
    bf16_t* Wqb = ws;                      // Wall = [Wq|Wk|Wv|Wo] bf16
    bf16_t* Wob = Wqb + 3 * WSZ;
    bf16_t* Qp  = Wob + WSZ;
    bf16_t* Kp  = Qp + MSZ;
    bf16_t* VtG = Kp + MSZ;
    bf16_t* shX = VtG + MSZ;               // vb (cast->gemm_qkv), then AO (attn->gemm_out)
    bf16_t* qb  = (bf16_t*)d_out;
    bf16_t* kb  = qb + MSZ;
    bf16_t* vb  = shX;
    bf16_t* AO  = shX;

    cast_all<<<dim3(2048, 7), 256, 0, stream>>>(Wq, Wk, Wv, Wo, q, k, v,
                                                ws, qb, kb, vb,
                                                DMODEL * DMODEL, M * DMODEL);

    const float qscale = 0.125f * 1.44269504088896f;   // 1/sqrt(64) * log2(e)
    gemm_qkv<<<dim3(M / 128, DMODEL / 128, 3), 256, 0, stream>>>(
        qb, kb, vb, Wqb, bq, bk, bv, Qp, Kp, VtG, M, qscale, S);

    attn_kernel<<<dim3(S / 256, B * NHEADS), 256, 0, stream>>>(Qp, Kp, VtG, AO, S);

    gemm_out<<<dim3(M / 128, DMODEL / 128), 256, 0, stream>>>(
        AO, Wob, bo, (float*)d_out, M, DMODEL, DMODEL);
}